// Round 1
// baseline (223.367 us; speedup 1.0000x reference)
//
#include <hip/hip_runtime.h>
#include <math.h>

#define K_TOT 32
#define K_IND 16
#define K_MLP 16
#define DHID  64

// ws layout: floats [0..16) = P, [16..32) = N, int flag at float-idx 32,
// row_ptr = ((int*)ws) + 64, length N+1.

// Precompute P_k = sum_{j: w1_j>0} w1_j*w2[j][k], N_k = sum_{j: w1_j<0} w1_j*w2[j][k]
// and a flag for "all b1 == 0" (enables the collapsed-MLP fast path).
__global__ void setup_kernel(const float* __restrict__ w1,
                             const float* __restrict__ b1,
                             const float* __restrict__ w2,
                             float* __restrict__ wsP,
                             float* __restrict__ wsN,
                             int* __restrict__ wsflag) {
    int t = threadIdx.x;  // 64 threads
    if (t < K_MLP) {
        float P = 0.f, Nn = 0.f;
        for (int j = 0; j < DHID; ++j) {
            float w = w1[j];
            float v = w2[j * K_MLP + t];
            P  += fmaxf(w, 0.f) * v;
            Nn += fminf(w, 0.f) * v;
        }
        wsP[t] = P;
        wsN[t] = Nn;
    }
    bool nz = (b1[t] != 0.f);
    unsigned long long mask = __ballot(nz);
    if (t == 0) *wsflag = (mask == 0ull) ? 1 : 0;
}

// row_ptr[n] = first edge e with receivers[e] >= n (receivers sorted ascending).
__global__ void rowptr_kernel(const int* __restrict__ recv, int* __restrict__ rp,
                              int E, int N) {
    int e = blockIdx.x * blockDim.x + threadIdx.x;
    if (e >= E) return;
    int r = recv[e];
    int rprev = (e == 0) ? -1 : recv[e - 1];
    for (int n = rprev + 1; n <= r; ++n) rp[n] = e;
    if (e == E - 1) {
        for (int n = r + 1; n <= N; ++n) rp[n] = E;
    }
}

// One wave (64 lanes) per node: lanes = 2 edge-slots x 32 channels.
// Channels 0..15: indicator path (count + sum of pd in the matching bin).
// Channels 16..31: online softmax over mlp_k with pd-weighted accumulator.
// Epilogue: fused out = relu(nodes@Wself + g@Wgath + bg) via shuffle broadcast.
__global__ __launch_bounds__(256) void graph_kernel(
        const float* __restrict__ nodes,
        const float* __restrict__ dist,
        const float* __restrict__ padv,
        const int*   __restrict__ send,
        const float* __restrict__ w1,
        const float* __restrict__ b1,
        const float* __restrict__ w2,
        const float* __restrict__ b2,
        const float* __restrict__ a_p,
        const float* __restrict__ b_p,
        const float* __restrict__ wg_self,
        const float* __restrict__ wg_gath,
        const float* __restrict__ bg,
        const float* __restrict__ wsP,
        const float* __restrict__ wsN,
        const int*   __restrict__ wsflag,
        const int*   __restrict__ rp,
        float* __restrict__ out,
        int N) {
    int wave = blockIdx.x * (blockDim.x >> 6) + (threadIdx.x >> 6);
    if (wave >= N) return;
    int n    = wave;
    int lane = threadIdx.x & 63;
    int c    = lane & 31;
    int eo   = lane >> 5;

    float a_c = fminf(fmaxf(a_p[0], 0.f), 1.f);
    float am  = 1.f - a_c;
    float bc  = fabsf(b_p[0]);
    bool  bsq = (bc == 2.0f);
    bool  fast = (*wsflag != 0);

    float Pk = 0.f, Nk = 0.f, b2k = 0.f;
    if (c >= K_IND) {
        Pk  = wsP[c - K_IND];
        Nk  = wsN[c - K_IND];
        b2k = b2[c - K_IND];
    }

    float nr = nodes[n * K_TOT + c];
    int e0 = rp[n], eEnd = rp[n + 1];

    // indicator-path state (c < 16)
    float cnt = 0.f, s_ind = 0.f;
    float lo = (float)c * 0.0625f;
    float hi = (float)(c + 1) * 0.0625f;
    // softmax-path state (c >= 16)
    float m = -INFINITY, l = 0.f, acc = 0.f;

    for (int e = e0 + eo; e < eEnd; e += 2) {
        float d  = dist[e];
        int   s  = send[e];
        float pe = padv[e];
        float ns = nodes[s * K_TOT + c];
        float t  = fabsf(a_c * nr - am * ns);
        float pd = bsq ? t * t : powf(t, bc);
        if (c < K_IND) {
            // strict interior of bin c (heaviside(...,0) semantics: boundary -> 0)
            if (d > lo && d < hi) { cnt += 1.f; s_ind += pe * pd; }
        } else {
            float mlp;
            if (fast) {
                mlp = fmaf(d, (d > 0.f ? Pk : Nk), b2k);
            } else {
                mlp = b2k;
                for (int j = 0; j < DHID; ++j) {
                    float h = fmaxf(fmaf(d, w1[j], b1[j]), 0.f);
                    mlp = fmaf(h, w2[j * K_MLP + (c - K_IND)], mlp);
                }
            }
            float mn = fmaxf(m, mlp);
            float al = __expf(m - mn);    // first edge: exp(-inf)=0, kills l*al
            float p  = __expf(mlp - mn);
            l   = fmaf(l, al, p);
            acc = fmaf(acc, al, p * pe * pd);
            m = mn;
        }
    }

    // merge the two half-wave (edge-interleaved) partial states
    cnt   += __shfl_xor(cnt, 32);
    s_ind += __shfl_xor(s_ind, 32);
    float m2 = __shfl_xor(m, 32);
    float l2 = __shfl_xor(l, 32);
    float a2 = __shfl_xor(acc, 32);
    float mn = fmaxf(m, m2);
    float f1 = __expf(m - mn);    // both halves empty -> NaN, guarded below
    float f2 = __expf(m2 - mn);
    l   = l * f1 + l2 * f2;
    acc = acc * f1 + a2 * f2;

    float g;
    if (c < K_IND) g = s_ind / (cnt + 1e-5f);
    else           g = (l > 0.f) ? (acc / l) : 0.f;  // empty segment -> 0 (NaN>0 false)

    // epilogue: out[n][c] = relu( sum_j nr_j*Wself[j][c] + g_j*Wgath[j][c] + bg[c] )
    // half eo=0 covers j=0..15, eo=1 covers j=16..31.
    float o = 0.f;
    int jbase = eo * 16;
#pragma unroll
    for (int jj = 0; jj < 16; ++jj) {
        int j = jbase + jj;
        float gj = __shfl(g, j);    // merged g identical in both halves
        float nj = __shfl(nr, j);
        o = fmaf(nj, wg_self[j * K_TOT + c], o);
        o = fmaf(gj, wg_gath[j * K_TOT + c], o);
    }
    o += __shfl_xor(o, 32);
    if (eo == 0) {
        o += bg[c];
        out[n * K_TOT + c] = fmaxf(o, 0.f);
    }
}

extern "C" void kernel_launch(void* const* d_in, const int* in_sizes, int n_in,
                              void* d_out, int out_size, void* d_ws, size_t ws_size,
                              hipStream_t stream) {
    const float* nodes   = (const float*)d_in[0];
    const float* dist    = (const float*)d_in[1];
    const float* padv    = (const float*)d_in[2];
    const int*   recv    = (const int*)d_in[3];
    const int*   send    = (const int*)d_in[4];
    const float* w1      = (const float*)d_in[5];
    const float* b1      = (const float*)d_in[6];
    const float* w2      = (const float*)d_in[7];
    const float* b2      = (const float*)d_in[8];
    const float* a_p     = (const float*)d_in[9];
    const float* b_p     = (const float*)d_in[10];
    const float* wg_self = (const float*)d_in[11];
    const float* wg_gath = (const float*)d_in[12];
    const float* bg      = (const float*)d_in[13];
    float* out = (float*)d_out;

    int N = in_sizes[0] / K_TOT;
    int E = in_sizes[1];

    float* wsf    = (float*)d_ws;
    float* wsP    = wsf;
    float* wsN    = wsf + 16;
    int*   wsflag = (int*)(wsf + 32);
    int*   rp     = (int*)d_ws + 64;

    setup_kernel<<<1, 64, 0, stream>>>(w1, b1, w2, wsP, wsN, wsflag);
    rowptr_kernel<<<(E + 255) / 256, 256, 0, stream>>>(recv, rp, E, N);
    graph_kernel<<<(N + 3) / 4, 256, 0, stream>>>(
        nodes, dist, padv, send, w1, b1, w2, b2, a_p, b_p,
        wg_self, wg_gath, bg, wsP, wsN, wsflag, rp, out, N);
}

// Round 2
// 187.394 us; speedup vs baseline: 1.1920x; 1.1920x over previous
//
#include <hip/hip_runtime.h>
#include <math.h>

#define K_TOT 32
#define K_IND 16
#define K_MLP 16
#define DHID  64

// ws layout: floats [0..16) = P, [16..32) = N, int flag at int-idx 32,
// row_ptr = ((int*)ws) + 64, length N+1.

// Fused prep: block 0 / wave 0 computes the collapsed-MLP constants
//   P_k = sum_{j: w1_j>0} w1_j*w2[j][k], N_k = sum_{j: w1_j<0} w1_j*w2[j][k]
// and flag = (all b1 == 0). All blocks build row_ptr from sorted receivers.
__global__ void prep_kernel(const int* __restrict__ recv, int E, int N,
                            const float* __restrict__ w1,
                            const float* __restrict__ b1,
                            const float* __restrict__ w2,
                            float* __restrict__ wsP,
                            float* __restrict__ wsN,
                            int* __restrict__ wsflag,
                            int* __restrict__ rp) {
    if (blockIdx.x == 0 && threadIdx.x < 64) {
        int t = threadIdx.x;
        if (t < K_MLP) {
            float P = 0.f, Nn = 0.f;
            for (int j = 0; j < DHID; ++j) {
                float w = w1[j];
                float v = w2[j * K_MLP + t];
                P  += fmaxf(w, 0.f) * v;
                Nn += fminf(w, 0.f) * v;
            }
            wsP[t] = P;
            wsN[t] = Nn;
        }
        bool nz = (b1[t] != 0.f);
        unsigned long long mask = __ballot(nz);
        if (t == 0) *wsflag = (mask == 0ull) ? 1 : 0;
    }
    int e = blockIdx.x * blockDim.x + threadIdx.x;
    if (e >= E) return;
    int r = recv[e];
    int rprev = (e == 0) ? -1 : recv[e - 1];
    for (int n = rprev + 1; n <= r; ++n) rp[n] = e;
    if (e == E - 1) {
        for (int n = r + 1; n <= N; ++n) rp[n] = E;
    }
}

// One wave per node. Lane layout: eg = lane>>4 (4 edge slots), cc = lane&15.
// Each lane owns channel cc (indicator path) AND channel cc+16 (softmax path)
// -> no intra-wave divergence; 4 edges per iteration.
// 2-deep software pipeline: stage A = compute, stage B = ns-gather in flight,
// stage C = edge scalars in flight.
__global__ __launch_bounds__(256) void graph_kernel(
        const float* __restrict__ nodes,
        const float* __restrict__ dist,
        const float* __restrict__ padv,
        const int*   __restrict__ send,
        const float* __restrict__ w1,
        const float* __restrict__ b1,
        const float* __restrict__ w2,
        const float* __restrict__ b2,
        const float* __restrict__ a_p,
        const float* __restrict__ b_p,
        const float* __restrict__ wg_self,
        const float* __restrict__ wg_gath,
        const float* __restrict__ bg,
        const float* __restrict__ wsP,
        const float* __restrict__ wsN,
        const int*   __restrict__ wsflag,
        const int*   __restrict__ rp,
        float* __restrict__ out,
        int N) {
    int wave = blockIdx.x * (blockDim.x >> 6) + (threadIdx.x >> 6);
    if (wave >= N) return;
    int n    = wave;
    int lane = threadIdx.x & 63;
    int eg   = lane >> 4;   // edge slot 0..3
    int cc   = lane & 15;   // channel pair index

    float a_c = fminf(fmaxf(a_p[0], 0.f), 1.f);
    float am  = 1.f - a_c;
    float bc  = fabsf(b_p[0]);
    bool  bsq = (bc == 2.0f);
    bool  fast = (*wsflag != 0);

    float Pk  = wsP[cc];
    float Nk  = wsN[cc];
    float b2k = b2[cc];

    float nr0 = nodes[(size_t)n * K_TOT + cc];
    float nr1 = nodes[(size_t)n * K_TOT + cc + 16];
    float anr0 = a_c * nr0;
    float anr1 = a_c * nr1;

    int e0 = rp[n], eEnd = rp[n + 1];
    int len = eEnd - e0;
    int T = (len + 3) >> 2;   // uniform trip count, tail masked per lane

    float lo = (float)cc * 0.0625f;
    float hi = (float)(cc + 1) * 0.0625f;

    // accumulator state
    float cnt = 0.f, si = 0.f;                    // indicator (channel cc)
    float m = -INFINITY, l = 0.f, acc = 0.f;      // softmax  (channel cc+16)

    // ---- pipeline prologue ----
    int  eA = e0 + eg;  bool vA = (eA < eEnd);
    float dA = -1.f, peA = 0.f; int sA = 0;
    if (vA) {
        dA  = __builtin_nontemporal_load(&dist[eA]);
        sA  = __builtin_nontemporal_load(&send[eA]);
        peA = __builtin_nontemporal_load(&padv[eA]);
    }
    int  eB = eA + 4;   bool vB = (eB < eEnd);
    float dB = -1.f, peB = 0.f; int sB = 0;
    if (vB) {
        dB  = __builtin_nontemporal_load(&dist[eB]);
        sB  = __builtin_nontemporal_load(&send[eB]);
        peB = __builtin_nontemporal_load(&padv[eB]);
    }
    float nsA0 = nodes[(size_t)sA * K_TOT + cc];
    float nsA1 = nodes[(size_t)sA * K_TOT + cc + 16];

    for (int it = 0; it < T; ++it) {
        // issue stage-C scalar loads (2 iterations ahead)
        int  eC = eB + 4;  bool vC = (eC < eEnd);
        float dC = -1.f, peC = 0.f; int sC = 0;
        if (vC) {
            dC  = __builtin_nontemporal_load(&dist[eC]);
            sC  = __builtin_nontemporal_load(&send[eC]);
            peC = __builtin_nontemporal_load(&padv[eC]);
        }
        // issue stage-B gather (1 iteration ahead; sB loaded 2 iters ago)
        float nsB0 = nodes[(size_t)sB * K_TOT + cc];
        float nsB1 = nodes[(size_t)sB * K_TOT + cc + 16];

        // ---- compute on stage A ----
        float t0 = fmaf(-am, nsA0, anr0);
        float t1 = fmaf(-am, nsA1, anr1);
        float pd0 = bsq ? t0 * t0 : powf(fabsf(t0), bc);
        float pd1 = bsq ? t1 * t1 : powf(fabsf(t1), bc);

        // indicator path (channel cc): strict bin interior, heaviside(.,0)
        bool inb = vA && (dA > lo) && (dA < hi);
        cnt += inb ? 1.f : 0.f;
        si  += inb ? peA * pd0 : 0.f;

        // softmax path (channel cc+16), online
        float mlp;
        if (fast) {
            mlp = fmaf(dA, (dA > 0.f ? Pk : Nk), b2k);
        } else {
            mlp = b2k;
            for (int j = 0; j < DHID; ++j) {
                float h = fmaxf(fmaf(dA, w1[j], b1[j]), 0.f);
                mlp = fmaf(h, w2[j * K_MLP + cc], mlp);
            }
        }
        float mlpv = vA ? mlp : -INFINITY;
        float mn = fmaxf(m, mlpv);
        float al = (m == -INFINITY) ? 0.f : __expf(m - mn);
        float p  = vA ? __expf(mlpv - mn) : 0.f;
        l   = fmaf(l, al, p);
        acc = fmaf(acc, al, p * (peA * pd1));
        m = mn;

        // rotate pipeline
        eA = eB; vA = vB; dA = dB; sA = sB; peA = peB;
        nsA0 = nsB0; nsA1 = nsB1;
        eB = eC; vB = vC; dB = dC; sB = sC; peB = peC;
    }

    // ---- merge the 4 edge-slot partial states (xor 16, then 32) ----
    {
        cnt += __shfl_xor(cnt, 16);
        si  += __shfl_xor(si, 16);
        float m2 = __shfl_xor(m, 16), l2 = __shfl_xor(l, 16), a2 = __shfl_xor(acc, 16);
        float mn = fmaxf(m, m2);
        float f1 = (m  == -INFINITY) ? 0.f : __expf(m  - mn);
        float f2 = (m2 == -INFINITY) ? 0.f : __expf(m2 - mn);
        l   = l * f1 + l2 * f2;
        acc = acc * f1 + a2 * f2;
        m = mn;
    }
    {
        cnt += __shfl_xor(cnt, 32);
        si  += __shfl_xor(si, 32);
        float m2 = __shfl_xor(m, 32), l2 = __shfl_xor(l, 32), a2 = __shfl_xor(acc, 32);
        float mn = fmaxf(m, m2);
        float f1 = (m  == -INFINITY) ? 0.f : __expf(m  - mn);
        float f2 = (m2 == -INFINITY) ? 0.f : __expf(m2 - mn);
        l   = l * f1 + l2 * f2;
        acc = acc * f1 + a2 * f2;
        m = mn;
    }

    float g_ind = si / (cnt + 1e-5f);
    float g_mlp = (l > 0.f) ? (acc / l) : 0.f;   // empty segment -> 0

    // ---- fused epilogue: out[n][oc] = relu(sum_j nr_j*Wself[j][oc] + g_j*Wgath[j][oc] + bg[oc])
    // lanes: h = lane>>5 covers j in [h*16, h*16+16); oc = lane&31.
    // source-lane trick: lane j (j<32) holds (g_ind,nr0) if (j>>4)&1==0 else (g_mlp,nr1),
    // which is exactly channel j.
    int h  = lane >> 5;
    int oc = lane & 31;
    float pre_g = ((lane >> 4) & 1) ? g_mlp : g_ind;
    float pre_n = ((lane >> 4) & 1) ? nr1 : nr0;

    float o = 0.f;
    int jbase = h * 16;
#pragma unroll
    for (int jj = 0; jj < 16; ++jj) {
        int j = jbase + jj;
        float gj = __shfl(pre_g, j);
        float nj = __shfl(pre_n, j);
        o = fmaf(nj, wg_self[j * K_TOT + oc], o);
        o = fmaf(gj, wg_gath[j * K_TOT + oc], o);
    }
    o += __shfl_xor(o, 32);
    if (h == 0) {
        out[(size_t)n * K_TOT + oc] = fmaxf(o + bg[oc], 0.f);
    }
}

extern "C" void kernel_launch(void* const* d_in, const int* in_sizes, int n_in,
                              void* d_out, int out_size, void* d_ws, size_t ws_size,
                              hipStream_t stream) {
    const float* nodes   = (const float*)d_in[0];
    const float* dist    = (const float*)d_in[1];
    const float* padv    = (const float*)d_in[2];
    const int*   recv    = (const int*)d_in[3];
    const int*   send    = (const int*)d_in[4];
    const float* w1      = (const float*)d_in[5];
    const float* b1      = (const float*)d_in[6];
    const float* w2      = (const float*)d_in[7];
    const float* b2      = (const float*)d_in[8];
    const float* a_p     = (const float*)d_in[9];
    const float* b_p     = (const float*)d_in[10];
    const float* wg_self = (const float*)d_in[11];
    const float* wg_gath = (const float*)d_in[12];
    const float* bg      = (const float*)d_in[13];
    float* out = (float*)d_out;

    int N = in_sizes[0] / K_TOT;
    int E = in_sizes[1];

    float* wsf    = (float*)d_ws;
    float* wsP    = wsf;
    float* wsN    = wsf + 16;
    int*   wsflag = (int*)d_ws + 32;
    int*   rp     = (int*)d_ws + 64;

    prep_kernel<<<(E + 255) / 256, 256, 0, stream>>>(recv, E, N, w1, b1, w2,
                                                     wsP, wsN, wsflag, rp);
    graph_kernel<<<(N + 3) / 4, 256, 0, stream>>>(
        nodes, dist, padv, send, w1, b1, w2, b2, a_p, b_p,
        wg_self, wg_gath, bg, wsP, wsN, wsflag, rp, out, N);
}

// Round 3
// 185.071 us; speedup vs baseline: 1.2069x; 1.0126x over previous
//
#include <hip/hip_runtime.h>
#include <math.h>

#define K_TOT 32
#define K_IND 16
#define K_MLP 16
#define DHID  64

// ws layout: floats [0..16) = P, [16..32) = N, int flag at int-idx 32,
// row_ptr = ((int*)ws) + 64, length N+1.

// Prep: block 0 wave 0 computes collapsed-MLP constants
//   P_k = sum_{j: w1_j>0} w1_j*w2[j][k], N_k = sum_{j: w1_j<0} w1_j*w2[j][k]
// and flag = (all b1 == 0). All threads t<=N: rp[t] = lower_bound(recv, t).
__global__ void prep_kernel(const int* __restrict__ recv, int E, int N,
                            const float* __restrict__ w1,
                            const float* __restrict__ b1,
                            const float* __restrict__ w2,
                            float* __restrict__ wsP,
                            float* __restrict__ wsN,
                            int* __restrict__ wsflag,
                            int* __restrict__ rp) {
    if (blockIdx.x == 0 && threadIdx.x < 64) {
        int t = threadIdx.x;
        if (t < K_MLP) {
            float P = 0.f, Nn = 0.f;
            for (int j = 0; j < DHID; ++j) {
                float w = w1[j];
                float v = w2[j * K_MLP + t];
                P  += fmaxf(w, 0.f) * v;
                Nn += fminf(w, 0.f) * v;
            }
            wsP[t] = P;
            wsN[t] = Nn;
        }
        bool nz = (b1[t] != 0.f);
        unsigned long long mask = __ballot(nz);
        if (t == 0) *wsflag = (mask == 0ull) ? 1 : 0;
    }
    int tid = blockIdx.x * blockDim.x + threadIdx.x;
    if (tid <= N) {
        int lo = 0, hi = E;
        while (lo < hi) {
            int mid = (lo + hi) >> 1;
            if (recv[mid] < tid) lo = mid + 1; else hi = mid;
        }
        rp[tid] = lo;
    }
}

// One wave per node. eg = lane>>4 (4 edge slots), cc = lane&15 (channel pair).
// Edge scalars are loaded 64-at-a-time coalesced (clamped idx -> no guards),
// then broadcast per 4-edge group via ds_bpermute. Fast path uses a bound-M
// softmax (M_k = |q_k| * max|d|) -> pure sums, no online rescale.
__global__ __launch_bounds__(256) void graph_kernel(
        const float* __restrict__ nodes,
        const float* __restrict__ dist,
        const float* __restrict__ padv,
        const int*   __restrict__ send,
        const float* __restrict__ w1,
        const float* __restrict__ b1,
        const float* __restrict__ w2,
        const float* __restrict__ b2,
        const float* __restrict__ a_p,
        const float* __restrict__ b_p,
        const float* __restrict__ wg_self,
        const float* __restrict__ wg_gath,
        const float* __restrict__ bg,
        const float* __restrict__ wsP,
        const float* __restrict__ wsN,
        const int*   __restrict__ wsflag,
        const int*   __restrict__ rp,
        float* __restrict__ out,
        int N) {
    int wave = blockIdx.x * (blockDim.x >> 6) + (threadIdx.x >> 6);
    if (wave >= N) return;
    int n    = wave;
    int lane = threadIdx.x & 63;
    int eg   = lane >> 4;   // edge slot 0..3
    int cc   = lane & 15;   // channel pair index

    float a_c = fminf(fmaxf(a_p[0], 0.f), 1.f);
    float am  = 1.f - a_c;
    float bc  = fabsf(b_p[0]);
    bool  bsq = (bc == 2.0f);
    bool  fast = (*wsflag != 0);

    float Pk  = wsP[cc];
    float Nk  = wsN[cc];

    float nr0 = nodes[n * K_TOT + cc];
    float nr1 = nodes[n * K_TOT + cc + 16];
    float anr0 = a_c * nr0;
    float anr1 = a_c * nr1;

    int e0 = rp[n], eEnd = rp[n + 1];
    int len = eEnd - e0;

    float lo = (float)cc * 0.0625f;
    float hi = (float)(cc + 1) * 0.0625f;

    float cnt = 0.f, si = 0.f;        // indicator (channel cc)
    float l = 0.f, acc = 0.f;         // softmax  (channel cc+16)
    float m_on = -INFINITY;           // online state, !fast path only

    float negM = 0.f;
    if (fast) {
        // pre-pass: max|d| over the segment (usually 1 iteration)
        float dm = 0.f;
        for (int base = 0; base < len; base += 64) {
            int idx = base + lane;
            int rem = len - 1;
            idx = idx < rem ? idx : rem;    // clamp
            float dv = dist[e0 + idx];
            dm = fmaxf(dm, fabsf(dv));
        }
#pragma unroll
        for (int off = 32; off; off >>= 1) dm = fmaxf(dm, __shfl_xor(dm, off));
        float qa = fmaxf(fabsf(Pk), fabsf(Nk));
        negM = -qa * dm;
    }

    int egb = eg << 2;   // bpermute byte index base for group 0

    for (int base = 0; base < len; base += 64) {
        int rem = len - base;           // > 0
        int ci = base + lane;
        int cmax = len - 1;
        ci = ci < cmax ? ci : cmax;     // clamp -> no overfetch, no guards
        int e = e0 + ci;
        float dl = dist[e];
        int   sl = send[e];
        float pl = padv[e];
        int nG = (rem + 3) >> 2;
        nG = nG < 16 ? nG : 16;
        int byteIdx = egb;
        for (int g2 = 0; g2 < nG; ++g2, byteIdx += 16) {
            float d  = __int_as_float(__builtin_amdgcn_ds_bpermute(byteIdx, __float_as_int(dl)));
            int   s  = __builtin_amdgcn_ds_bpermute(byteIdx, sl);
            float pe = __int_as_float(__builtin_amdgcn_ds_bpermute(byteIdx, __float_as_int(pl)));
            bool valid = (base + (g2 << 2) + eg) < len;

            const float* nsrow = nodes + (s * K_TOT + cc);
            float ns0 = nsrow[0];
            float ns1 = nsrow[16];

            float t0 = fmaf(-am, ns0, anr0);
            float t1 = fmaf(-am, ns1, anr1);
            float pd0 = bsq ? t0 * t0 : powf(fabsf(t0), bc);
            float pd1 = bsq ? t1 * t1 : powf(fabsf(t1), bc);

            bool inb = valid && (d > lo) && (d < hi);
            cnt += inb ? 1.f : 0.f;
            si  += inb ? pe * pd0 : 0.f;

            if (fast) {
                float q = (d > 0.f) ? Pk : Nk;
                float p = __expf(fmaf(d, q, negM));
                p = valid ? p : 0.f;
                l += p;
                acc = fmaf(p, pe * pd1, acc);
            } else {
                float mlp = 0.f;   // b2 cancels in the softmax ratio
                for (int j = 0; j < DHID; ++j) {
                    float h = fmaxf(fmaf(d, w1[j], b1[j]), 0.f);
                    mlp = fmaf(h, w2[j * K_MLP + cc], mlp);
                }
                float mlpv = valid ? mlp : -INFINITY;
                float mn = fmaxf(m_on, mlpv);
                float al = (m_on == -INFINITY) ? 0.f : __expf(m_on - mn);
                float p  = valid ? __expf(mlpv - mn) : 0.f;
                l   = fmaf(l, al, p);
                acc = fmaf(acc, al, p * pe * pd1);
                m_on = mn;
            }
        }
    }

    // merge the 4 edge-slot partials (xor 16, then 32)
#pragma unroll
    for (int off = 16; off <= 32; off <<= 1) {
        cnt += __shfl_xor(cnt, off);
        si  += __shfl_xor(si, off);
        if (fast) {
            l   += __shfl_xor(l, off);
            acc += __shfl_xor(acc, off);
        } else {
            float m2 = __shfl_xor(m_on, off), l2 = __shfl_xor(l, off), a2 = __shfl_xor(acc, off);
            float mn = fmaxf(m_on, m2);
            float f1 = (m_on == -INFINITY) ? 0.f : __expf(m_on - mn);
            float f2 = (m2   == -INFINITY) ? 0.f : __expf(m2 - mn);
            l   = l * f1 + l2 * f2;
            acc = acc * f1 + a2 * f2;
            m_on = mn;
        }
    }

    float g_ind = si / (cnt + 1e-5f);
    float g_mlp = (l > 0.f) ? (acc / l) : 0.f;   // empty segment -> 0

    // fused epilogue: out[n][oc] = relu(sum_j nr_j*Wself[j][oc] + g_j*Wgath[j][oc] + bg[oc])
    // h = lane>>5 covers j in [h*16, h*16+16); oc = lane&31.
    // lane j (j<32) holds (g,nr) of exactly channel j via the pre_* selects.
    int h  = lane >> 5;
    int oc = lane & 31;
    float pre_g = ((lane >> 4) & 1) ? g_mlp : g_ind;
    float pre_n = ((lane >> 4) & 1) ? nr1 : nr0;

    float o = 0.f;
    int jbase = h * 16;
#pragma unroll
    for (int jj = 0; jj < 16; ++jj) {
        int j = jbase + jj;
        float gj = __shfl(pre_g, j);
        float nj = __shfl(pre_n, j);
        o = fmaf(nj, wg_self[j * K_TOT + oc], o);
        o = fmaf(gj, wg_gath[j * K_TOT + oc], o);
    }
    o += __shfl_xor(o, 32);
    if (h == 0) {
        out[n * K_TOT + oc] = fmaxf(o + bg[oc], 0.f);
    }
}

extern "C" void kernel_launch(void* const* d_in, const int* in_sizes, int n_in,
                              void* d_out, int out_size, void* d_ws, size_t ws_size,
                              hipStream_t stream) {
    const float* nodes   = (const float*)d_in[0];
    const float* dist    = (const float*)d_in[1];
    const float* padv    = (const float*)d_in[2];
    const int*   recv    = (const int*)d_in[3];
    const int*   send    = (const int*)d_in[4];
    const float* w1      = (const float*)d_in[5];
    const float* b1      = (const float*)d_in[6];
    const float* w2      = (const float*)d_in[7];
    const float* b2      = (const float*)d_in[8];
    const float* a_p     = (const float*)d_in[9];
    const float* b_p     = (const float*)d_in[10];
    const float* wg_self = (const float*)d_in[11];
    const float* wg_gath = (const float*)d_in[12];
    const float* bg      = (const float*)d_in[13];
    float* out = (float*)d_out;

    int N = in_sizes[0] / K_TOT;
    int E = in_sizes[1];

    float* wsf    = (float*)d_ws;
    float* wsP    = wsf;
    float* wsN    = wsf + 16;
    int*   wsflag = (int*)d_ws + 32;
    int*   rp     = (int*)d_ws + 64;

    prep_kernel<<<(N + 1 + 255) / 256, 256, 0, stream>>>(recv, E, N, w1, b1, w2,
                                                         wsP, wsN, wsflag, rp);
    graph_kernel<<<(N + 3) / 4, 256, 0, stream>>>(
        nodes, dist, padv, send, w1, b1, w2, b2, a_p, b_p,
        wg_self, wg_gath, bg, wsP, wsN, wsflag, rp, out, N);
}